// Round 3
// baseline (397.521 us; speedup 1.0000x reference)
//
#include <hip/hip_runtime.h>
#include <hip/hip_bf16.h>

// RainReservoirEncoder: x_{t+1} = tanh(W x_t + w_in u_t), T=4096, hidden=16, B=8192.
// Latency-bound serial recurrence: wall = T x per-step critical path.
// Per wave: 16 batch chains via mfma_f32_16x16x16_f16 ping-pong identity:
// D frag (col=lane&15=batch, row=(lane>>4)*4+q=hidden) is bit-position-identical
// to the next step's B frag (n=lane&15, k=(lane>>4)*4+e) => zero cross-lane
// movement per step. f16 (11-bit mantissa) lets one MFMA carry W exactly enough
// (no hi/lo split) and v_cvt_pkrtz_f16_f32 packs the state in 2 ops.

#define B_SZ 8192
#define T_SZ 4096
#define H 16

typedef __attribute__((ext_vector_type(2))) __fp16 f16x2;
typedef __attribute__((ext_vector_type(4))) __fp16 f16x4;
typedef __attribute__((ext_vector_type(4))) float f32x4;

static __device__ __forceinline__ f32x4 mfma_f16(f16x4 a, f16x4 b, f32x4 c) {
  return __builtin_amdgcn_mfma_f32_16x16x16f16(a, b, c, 0, 0, 0);
}

__global__ __launch_bounds__(128) void rre_kernel(
    const float* __restrict__ rain,   // (B, T, 1) f32
    const float* __restrict__ w_in,   // (16, 1)  f32
    const float* __restrict__ w,      // (16, 16) f32
    float* __restrict__ out) {        // (B, 16)  f32
  const int lane = threadIdx.x & 63;
  const int wgrp = threadIdx.x >> 6;            // wave in block (0..1)
  const int col  = lane & 15;                   // batch slot within group
  const int grp  = lane >> 4;                   // k/row group (0..3)
  const int gid  = blockIdx.x * 2 + wgrp;       // 0..511
  const int b    = gid * 16 + col;

  const float KTANH = 2.8853900817779268f;      // 2/ln(2): exp2(KTANH*p) = e^{2p}

  // A = KTANH*W in f16. Lane holds A[m=col][k=grp*4+e], e=0..3.
  f32x4 wf = *(const f32x4*)(w + col * H + grp * 4);
  f16x4 wfrag;
  wfrag.x = (__fp16)(wf.x * KTANH);
  wfrag.y = (__fp16)(wf.y * KTANH);
  wfrag.z = (__fp16)(wf.z * KTANH);
  wfrag.w = (__fp16)(wf.w * KTANH);

  // C init term: lane needs KTANH*w_in[i] for i = grp*4+q (f32, exact).
  f32x4 win = *(const f32x4*)(w_in + grp * 4);
  win.x *= KTANH; win.y *= KTANH; win.z *= KTANH; win.w *= KTANH;

  // Input stream for this lane's batch row. 4 u's per float4 chunk.
  const float* up = rain + (size_t)b * T_SZ;
  const int NC = T_SZ / 4;  // 1024 chunks

  auto LD = [&](int cc) -> f32x4 {
    cc = (cc < NC) ? cc : (NC - 1);             // clamp tail prefetch (in-bounds, unused)
    return *(const f32x4*)(up + cc * 4);
  };

  // 4-deep named prefetch ring (static indexing only — no scratch, rule #20).
  f32x4 bufA = LD(0), bufB = LD(1), bufC = LD(2), bufD = LD(3);

  f16x4 xfrag = {(__fp16)0.f, (__fp16)0.f, (__fp16)0.f, (__fp16)0.f};
  f32x4 xout = {0.f, 0.f, 0.f, 0.f};

#define STEP(u)                                                   \
  {                                                               \
    f32x4 acc;                                                    \
    acc.x = (u) * win.x; acc.y = (u) * win.y;                     \
    acc.z = (u) * win.z; acc.w = (u) * win.w;                     \
    acc = mfma_f16(wfrag, xfrag, acc);                            \
    /* tanh(p) = 1 - 2/(1+e^{2p}); acc = 2p/ln2 already */        \
    float e0 = __builtin_amdgcn_exp2f(acc.x);                     \
    float e1 = __builtin_amdgcn_exp2f(acc.y);                     \
    float e2 = __builtin_amdgcn_exp2f(acc.z);                     \
    float e3 = __builtin_amdgcn_exp2f(acc.w);                     \
    float r0 = __builtin_amdgcn_rcpf(e0 + 1.0f);                  \
    float r1 = __builtin_amdgcn_rcpf(e1 + 1.0f);                  \
    float r2 = __builtin_amdgcn_rcpf(e2 + 1.0f);                  \
    float r3 = __builtin_amdgcn_rcpf(e3 + 1.0f);                  \
    xout.x = __builtin_fmaf(-2.0f, r0, 1.0f);                     \
    xout.y = __builtin_fmaf(-2.0f, r1, 1.0f);                     \
    xout.z = __builtin_fmaf(-2.0f, r2, 1.0f);                     \
    xout.w = __builtin_fmaf(-2.0f, r3, 1.0f);                     \
    f16x2 lo = __builtin_amdgcn_cvt_pkrtz(xout.x, xout.y);        \
    f16x2 hi = __builtin_amdgcn_cvt_pkrtz(xout.z, xout.w);        \
    xfrag = __builtin_shufflevector(lo, hi, 0, 1, 2, 3);          \
  }

#define CHUNK(buf) { STEP(buf.x) STEP(buf.y) STEP(buf.z) STEP(buf.w) }

#pragma unroll 1
  for (int c = 0; c < NC; c += 4) {
    CHUNK(bufA); bufA = LD(c + 4);   // consumed 12-16 steps later (covers HBM latency)
    CHUNK(bufB); bufB = LD(c + 5);
    CHUNK(bufC); bufC = LD(c + 6);
    CHUNK(bufD); bufD = LD(c + 7);
  }
#undef CHUNK
#undef STEP

  // Final state: lane holds x[b][grp*4+q] in xout (f32, pre-f16-rounding).
  *(f32x4*)(out + (size_t)b * H + grp * 4) = xout;
}

extern "C" void kernel_launch(void* const* d_in, const int* in_sizes, int n_in,
                              void* d_out, int out_size, void* d_ws, size_t ws_size,
                              hipStream_t stream) {
  const float* rain = (const float*)d_in[0];
  const float* w_in = (const float*)d_in[1];
  const float* w    = (const float*)d_in[2];
  float* out = (float*)d_out;
  (void)in_sizes; (void)n_in; (void)out_size; (void)d_ws; (void)ws_size;

  // 512 waves (16 chains each) -> 256 blocks x 128 threads (<=1 wave/SIMD:
  // trans-pipe issue is on the critical path; don't share SIMDs).
  rre_kernel<<<B_SZ / 32, 128, 0, stream>>>(rain, w_in, w, out);
}

// Round 4
// 391.005 us; speedup vs baseline: 1.0167x; 1.0167x over previous
//
#include <hip/hip_runtime.h>
#include <hip/hip_bf16.h>

// RainReservoirEncoder: x_{t+1} = tanh(W x_t + w_in u_t), T=4096, hidden=16, B=8192.
// Serial nonlinear recurrence: wall = T x per-step critical path (latency-bound,
// ~230cy/step measured; removing MFMA+VALU work changed nothing -> trans-pipe
// suspected dominant). This round: cut trans ops 8 -> 5 per step.
//
//  - State carried as r = 1/(1+e^{2p}) (x = 1-2r), so the MFMA absorbs the
//    affine map: y = base + K*w_in*u + mfma(A', r), A' = f16(-2K*W),
//    base = -0.5*rowsum(A') (computed from the f16-rounded entries so the
//    W-error structure matches the proven x-form kernel exactly).
//  - Montgomery batch-rcp: one v_rcp for all four 1/(1+e_i):
//    P = d0 d1 d2 d3; R = rcp(P); r_i = R * prod(others). Rel err ~1e-7.
//  - MFMA ping-pong: D frag (col=lane&15=batch, row=(lane>>4)*4+q) is
//    bit-position-identical to the next step's B frag -> no cross-lane moves.

#define B_SZ 8192
#define T_SZ 4096
#define H 16

typedef __attribute__((ext_vector_type(4))) __fp16 f16x4;
typedef __attribute__((ext_vector_type(4))) float f32x4;

static __device__ __forceinline__ f32x4 mfma_f16(f16x4 a, f16x4 b, f32x4 c) {
  return __builtin_amdgcn_mfma_f32_16x16x16f16(a, b, c, 0, 0, 0);
}

__global__ __launch_bounds__(128) void rre_kernel(
    const float* __restrict__ rain,   // (B, T, 1) f32
    const float* __restrict__ w_in,   // (16, 1)  f32
    const float* __restrict__ w,      // (16, 16) f32
    float* __restrict__ out) {        // (B, 16)  f32
  const int lane = threadIdx.x & 63;
  const int wgrp = threadIdx.x >> 6;            // wave in block (0..1)
  const int col  = lane & 15;                   // batch slot within group
  const int grp  = lane >> 4;                   // row/k group (0..3)
  const int gid  = blockIdx.x * 2 + wgrp;       // 0..511
  const int b    = gid * 16 + col;

  const float KTANH = 2.8853900817779268f;      // 2/ln2: exp2(K*p) = e^{2p}
  const float M2K   = -2.0f * KTANH;

  // A' = f16(-2K*W). Lane holds A'[m=col][k=grp*4+e], e=0..3.
  f32x4 wf = *(const f32x4*)(w + col * H + grp * 4);
  f16x4 wfrag;
  wfrag.x = (__fp16)(wf.x * M2K);
  wfrag.y = (__fp16)(wf.y * M2K);
  wfrag.z = (__fp16)(wf.z * M2K);
  wfrag.w = (__fp16)(wf.w * M2K);

  // base_q = -0.5 * sum_j f32(f16(-2K*W[row][j])), row = grp*4+q  (q = 0..3).
  // Using the f16-rounded entries makes rowsum error cancel against the MFMA's
  // A'-error: y = K * sum_j Wtilde[i][j] (1 - 2 r_j), Wtilde = f16-perturbed W.
  float bq0 = 0.f, bq1 = 0.f, bq2 = 0.f, bq3 = 0.f;
#pragma unroll
  for (int j = 0; j < H; ++j) {
    bq0 += (float)(__fp16)(M2K * w[(grp * 4 + 0) * H + j]);
    bq1 += (float)(__fp16)(M2K * w[(grp * 4 + 1) * H + j]);
    bq2 += (float)(__fp16)(M2K * w[(grp * 4 + 2) * H + j]);
    bq3 += (float)(__fp16)(M2K * w[(grp * 4 + 3) * H + j]);
  }
  f32x4 base;
  base.x = -0.5f * bq0; base.y = -0.5f * bq1;
  base.z = -0.5f * bq2; base.w = -0.5f * bq3;

  // K * w_in[row] for row = grp*4+q (f32, exact; INPUT_DIM=1).
  f32x4 kwin = *(const f32x4*)(w_in + grp * 4);
  kwin.x *= KTANH; kwin.y *= KTANH; kwin.z *= KTANH; kwin.w *= KTANH;

  // Input stream for this lane's batch row. 4 u's per float4 chunk.
  const float* up = rain + (size_t)b * T_SZ;
  const int NC = T_SZ / 4;  // 1024 chunks

  auto LD = [&](int cc) -> f32x4 {
    cc = (cc < NC) ? cc : (NC - 1);             // clamp tail prefetch
    return *(const f32x4*)(up + cc * 4);
  };

  // 4-deep named prefetch ring (static indexing only — rule #20).
  f32x4 bufA = LD(0), bufB = LD(1), bufC = LD(2), bufD = LD(3);

  f16x4 rfrag = {(__fp16)0.5f, (__fp16)0.5f, (__fp16)0.5f, (__fp16)0.5f};  // x0=0 -> r0=0.5
  f32x4 rs = {0.5f, 0.5f, 0.5f, 0.5f};          // f32 copy of last r (for epilogue)

#define STEP(u)                                                    \
  {                                                                \
    f32x4 acc;                                                     \
    acc.x = __builtin_fmaf((u), kwin.x, base.x);                   \
    acc.y = __builtin_fmaf((u), kwin.y, base.y);                   \
    acc.z = __builtin_fmaf((u), kwin.z, base.z);                   \
    acc.w = __builtin_fmaf((u), kwin.w, base.w);                   \
    acc = mfma_f16(wfrag, rfrag, acc);          /* acc = y = K*p */\
    float e0 = __builtin_amdgcn_exp2f(acc.x);                      \
    float e1 = __builtin_amdgcn_exp2f(acc.y);                      \
    float e2 = __builtin_amdgcn_exp2f(acc.z);                      \
    float e3 = __builtin_amdgcn_exp2f(acc.w);                      \
    float d0 = e0 + 1.0f, d1 = e1 + 1.0f;                          \
    float d2 = e2 + 1.0f, d3 = e3 + 1.0f;                          \
    float s01 = d0 * d1, s23 = d2 * d3;                            \
    float P = s01 * s23;                                           \
    float R = __builtin_amdgcn_rcpf(P);         /* 1 trans for 4 */\
    float R01 = R * s23, R23 = R * s01;                            \
    rs.x = R01 * d1; rs.y = R01 * d0;                              \
    rs.z = R23 * d3; rs.w = R23 * d2;                              \
    rfrag.x = (__fp16)rs.x; rfrag.y = (__fp16)rs.y;  /* RNE cvt */ \
    rfrag.z = (__fp16)rs.z; rfrag.w = (__fp16)rs.w;                \
  }

#define CHUNK(buf) { STEP(buf.x) STEP(buf.y) STEP(buf.z) STEP(buf.w) }

#pragma unroll 1
  for (int c = 0; c < NC; c += 4) {
    CHUNK(bufA); bufA = LD(c + 4);   // consumed 12-16 steps later
    CHUNK(bufB); bufB = LD(c + 5);
    CHUNK(bufC); bufC = LD(c + 6);
    CHUNK(bufD); bufD = LD(c + 7);
  }
#undef CHUNK
#undef STEP

  // x = 1 - 2 r (f32, from the pre-rounding r of the last step).
  f32x4 xo;
  xo.x = __builtin_fmaf(-2.0f, rs.x, 1.0f);
  xo.y = __builtin_fmaf(-2.0f, rs.y, 1.0f);
  xo.z = __builtin_fmaf(-2.0f, rs.z, 1.0f);
  xo.w = __builtin_fmaf(-2.0f, rs.w, 1.0f);
  *(f32x4*)(out + (size_t)b * H + grp * 4) = xo;
}

extern "C" void kernel_launch(void* const* d_in, const int* in_sizes, int n_in,
                              void* d_out, int out_size, void* d_ws, size_t ws_size,
                              hipStream_t stream) {
  const float* rain = (const float*)d_in[0];
  const float* w_in = (const float*)d_in[1];
  const float* w    = (const float*)d_in[2];
  float* out = (float*)d_out;
  (void)in_sizes; (void)n_in; (void)out_size; (void)d_ws; (void)ws_size;

  // 512 waves (16 chains each) -> 256 blocks x 128 threads (~1 wave/SIMD).
  rre_kernel<<<B_SZ / 32, 128, 0, stream>>>(rain, w_in, w, out);
}